// Round 5
// baseline (516.904 us; speedup 1.0000x reference)
//
#include <hip/hip_runtime.h>
#include <hip/hip_fp16.h>

#define NN 30000
#define NE 480000
#define CC 32
#define TT 12
#define CT 384            /* C*T */
#define CT2 192           /* CT/2 half2 words per row */
#define GPB 4             /* nodes per block in fused kernel */
#define NTASK (GPB * 4)   /* 16 */
#define TOT (4 * NN)      /* 120000 */
#define NB  118           /* ceil(TOT/1024) */

// ---------------- x -> fp16 conversion ----------------

__global__ void conv_kernel(const float2* __restrict__ x2, __half2* __restrict__ xh) {
    int i = blockIdx.x * blockDim.x + threadIdx.x;
    if (i < NN * CT2) {
        float2 v = x2[i];
        xh[i] = __floats2half2_rn(v.x, v.y);
    }
}

// ---------------- CSR build ----------------

__global__ void hist_kernel(const int* __restrict__ ei0, const int* __restrict__ ei1,
                            const int* __restrict__ ei2, const int* __restrict__ ei3,
                            int* __restrict__ cnt) {
    int e = blockIdx.x * blockDim.x + threadIdx.x;
    int b = blockIdx.y;
    if (e >= NE) return;
    const int* ei = (b == 0) ? ei0 : (b == 1) ? ei1 : (b == 2) ? ei2 : ei3;
    atomicAdd(&cnt[b * NN + ei[NE + e]], 1);   // dst row
}

// coalesced 3-phase scan over TOT elements
__global__ void scanA_kernel(const int* __restrict__ cnt,
                             int* __restrict__ pre, int* __restrict__ bsum) {
    __shared__ int s[1024];
    int tid = threadIdx.x;
    int i = blockIdx.x * 1024 + tid;
    int v = (i < TOT) ? cnt[i] : 0;
    s[tid] = v;
    __syncthreads();
    for (int off = 1; off < 1024; off <<= 1) {
        int t = (tid >= off) ? s[tid - off] : 0;
        __syncthreads();
        s[tid] += t;
        __syncthreads();
    }
    if (i < TOT) pre[i] = s[tid] - v;          // exclusive in-block
    if (tid == 1023) bsum[blockIdx.x] = s[1023];
}

__global__ void scanB_kernel(const int* __restrict__ bsum,
                             int* __restrict__ bbase, int* __restrict__ offs) {
    __shared__ int s[128];
    int tid = threadIdx.x;
    int v = (tid < NB) ? bsum[tid] : 0;
    s[tid] = v;
    __syncthreads();
    for (int off = 1; off < 128; off <<= 1) {
        int t = (tid >= off) ? s[tid - off] : 0;
        __syncthreads();
        s[tid] += t;
        __syncthreads();
    }
    if (tid < NB) bbase[tid] = s[tid] - v;
    if (tid == 127) offs[TOT] = s[127];
}

__global__ void scanC_kernel(const int* __restrict__ pre, const int* __restrict__ bbase,
                             int* __restrict__ offs, int* __restrict__ cur) {
    int i = blockIdx.x * 1024 + threadIdx.x;
    if (i < TOT) {
        int o = bbase[blockIdx.x] + pre[i];
        offs[i] = o;
        cur[i] = o;
    }
}

// pack edge as u32: src in [0:16), fp16 weight in [16:32)
__global__ void scatter_kernel(const int* __restrict__ ei0, const int* __restrict__ ei1,
                               const int* __restrict__ ei2, const int* __restrict__ ei3,
                               const float* __restrict__ ew0, const float* __restrict__ ew1,
                               const float* __restrict__ ew2, const float* __restrict__ ew3,
                               int* __restrict__ cur, unsigned int* __restrict__ pairs) {
    int e = blockIdx.x * blockDim.x + threadIdx.x;
    int b = blockIdx.y;
    if (e >= NE) return;
    const int*   ei = (b == 0) ? ei0 : (b == 1) ? ei1 : (b == 2) ? ei2 : ei3;
    const float* ew = (b == 0) ? ew0 : (b == 1) ? ew1 : (b == 2) ? ew2 : ew3;
    int d = ei[NE + e];
    int pos = atomicAdd(&cur[b * NN + d], 1);
    unsigned int w16 = (unsigned int)__half_as_ushort(__float2half_rn(ew[e]));
    pairs[pos] = (unsigned int)ei[e] | (w16 << 16);
}

// ---------------- fused gather (fp16 x, wave-per-node, scalar pair path) ----------------

#define GATHER_BODY(MASKED)                                                        \
    {                                                                              \
        unsigned int w32[8];                                                       \
        _Pragma("unroll")                                                          \
        for (int u = 0; u < 8; ++u) {                                              \
            if (MASKED) w32[u] = (j + u < c) ? pw[j + u] : 0u;                     \
            else        w32[u] = pw[j + u];                                        \
        }                                                                          \
        uint3 vv[8];                                                               \
        _Pragma("unroll")                                                          \
        for (int u = 0; u < 8; ++u) {                                              \
            const char* rowp = xh + (size_t)(w32[u] & 0xFFFFu) * 768;              \
            vv[u] = *(const uint3*)(rowp + lane12);                                \
        }                                                                          \
        _Pragma("unroll")                                                          \
        for (int u = 0; u < 8; ++u) {                                              \
            float w = __half2float(__ushort_as_half((unsigned short)(w32[u] >> 16)));\
            float2 f0 = __half22float2(*(const __half2*)&vv[u].x);                 \
            float2 f1 = __half22float2(*(const __half2*)&vv[u].y);                 \
            float2 f2 = __half22float2(*(const __half2*)&vv[u].z);                 \
            a0 = fmaf(w, f0.x, a0); a1 = fmaf(w, f0.y, a1);                        \
            a2 = fmaf(w, f1.x, a2); a3 = fmaf(w, f1.y, a3);                        \
            a4 = fmaf(w, f2.x, a4); a5 = fmaf(w, f2.y, a5);                        \
        }                                                                          \
    }

__global__ __launch_bounds__(256, 8)
void fused_kernel(const char* __restrict__ xh,      // fp16 x rows, 768 B stride
                  const unsigned int* __restrict__ pairs,
                  const int* __restrict__ offs,
                  const float* __restrict__ W0, const float* __restrict__ W1,
                  const float* __restrict__ W2, const float* __restrict__ W3,
                  const float* __restrict__ bias, float* __restrict__ out) {
    __shared__ __half2 aggS[NTASK * CT2];   // 16 x 192 x 4B = 12 KB
    const int tid  = threadIdx.x;
    const int wave = tid >> 6;              // 0..3 -> node g = wave
    const int lane = tid & 63;
    const int n0 = blockIdx.x * GPB;
    const int lane12 = lane * 12;

#pragma unroll
    for (int k = 0; k < 4; ++k) {
        const int row = __builtin_amdgcn_readfirstlane(k * NN + n0 + wave);
        const int b0 = offs[row];
        const int c  = offs[row + 1] - b0;
        const unsigned int* __restrict__ pw = pairs + b0;
        float a0 = 0.f, a1 = 0.f, a2 = 0.f, a3 = 0.f, a4 = 0.f, a5 = 0.f;
        int j = 0;
        for (; j + 8 <= c; j += 8) GATHER_BODY(0)
        if (j < c)                 GATHER_BODY(1)
        __half2* aU = &aggS[(wave * 4 + k) * CT2 + lane * 3];
        aU[0] = __floats2half2_rn(a0, a1);
        aU[1] = __floats2half2_rn(a2, a3);
        aU[2] = __floats2half2_rn(a4, a5);
    }
    __syncthreads();

    // ---- matmul: slots (g,q,t), 4 channels each; 384 slots over 256 threads ----
    const __half* __restrict__ aggH = (const __half*)aggS;
    const float* Ws[4] = { W0, W1, W2, W3 };
    for (int slot = tid; slot < GPB * 96; slot += 256) {
        int g = slot / 96;
        int rem = slot % 96;
        int q = rem / TT;       // 0..7
        int t = rem % TT;       // 0..11
        float acc[4];
#pragma unroll
        for (int i = 0; i < 4; ++i) acc[i] = bias[q * 4 + i];
#pragma unroll
        for (int b = 0; b < 4; ++b) {
            const float* __restrict__ Wb = Ws[b];
            const __half* __restrict__ aL = &aggH[(g * 4 + b) * CT];
#pragma unroll
            for (int h = 0; h < 2; ++h) {
                float row[16];
#pragma unroll
                for (int kk = 0; kk < 16; ++kk)
                    row[kk] = __half2float(aL[(h * 16 + kk) * TT + t]);
#pragma unroll
                for (int kk = 0; kk < 16; ++kk) {
#pragma unroll
                    for (int i = 0; i < 4; ++i)
                        acc[i] = fmaf(row[kk], Wb[(h * 16 + kk) * CC + q * 4 + i], acc[i]);
                }
            }
        }
#pragma unroll
        for (int i = 0; i < 4; ++i)
            out[(n0 + g) * CT + (q * 4 + i) * TT + t] = acc[i];
    }
}

// ---------------- launch ----------------

extern "C" void kernel_launch(void* const* d_in, const int* in_sizes, int n_in,
                              void* d_out, int out_size, void* d_ws, size_t ws_size,
                              hipStream_t stream) {
    const float* x    = (const float*)d_in[0];
    const float* bias = (const float*)d_in[13];
    const int*   ei[4] = { (const int*)d_in[1], (const int*)d_in[4],
                           (const int*)d_in[7], (const int*)d_in[10] };
    const float* ew[4] = { (const float*)d_in[2], (const float*)d_in[5],
                           (const float*)d_in[8], (const float*)d_in[11] };
    const float* W[4]  = { (const float*)d_in[3], (const float*)d_in[6],
                           (const float*)d_in[9], (const float*)d_in[12] };
    float* out = (float*)d_out;

    char* ws = (char*)d_ws;
    size_t OFF_PAIRS = 0;                                     // 4E u32 = 7.68 MB
    size_t OFF_XH    = OFF_PAIRS + (size_t)4 * NE * 4;        // N*CT2 half2 = 23.04 MB
    size_t OFF_CNT   = OFF_XH    + (size_t)NN * CT2 * 4;      // TOT int
    size_t OFF_OFFS  = OFF_CNT   + (size_t)TOT * 4;           // TOT+1 int
    size_t OFF_CUR   = OFF_OFFS  + (size_t)(TOT + 1) * 4;     // TOT int
    size_t OFF_PRE   = OFF_CUR   + (size_t)TOT * 4;           // TOT int
    size_t OFF_BSUM  = OFF_PRE   + (size_t)TOT * 4;           // 128 int
    size_t OFF_BBASE = OFF_BSUM  + (size_t)128 * 4;           // 128 int

    unsigned int* pairs = (unsigned int*)(ws + OFF_PAIRS);
    char*         xh    = ws + OFF_XH;
    int* cnt   = (int*)(ws + OFF_CNT);
    int* offs  = (int*)(ws + OFF_OFFS);
    int* cur   = (int*)(ws + OFF_CUR);
    int* pre   = (int*)(ws + OFF_PRE);
    int* bsum  = (int*)(ws + OFF_BSUM);
    int* bbase = (int*)(ws + OFF_BBASE);

    hipMemsetAsync(cnt, 0, (size_t)TOT * 4, stream);

    conv_kernel<<<(NN * CT2 + 255) / 256, 256, 0, stream>>>((const float2*)x, (__half2*)xh);

    dim3 eg((NE + 255) / 256, 4);
    hist_kernel<<<eg, 256, 0, stream>>>(ei[0], ei[1], ei[2], ei[3], cnt);
    scanA_kernel<<<NB, 1024, 0, stream>>>(cnt, pre, bsum);
    scanB_kernel<<<1, 128, 0, stream>>>(bsum, bbase, offs);
    scanC_kernel<<<NB, 1024, 0, stream>>>(pre, bbase, offs, cur);
    scatter_kernel<<<eg, 256, 0, stream>>>(ei[0], ei[1], ei[2], ei[3],
                                           ew[0], ew[1], ew[2], ew[3],
                                           cur, pairs);

    fused_kernel<<<NN / GPB, 256, 0, stream>>>(xh, pairs, offs,
                                               W[0], W[1], W[2], W[3],
                                               bias, out);
}